// Round 9
// baseline (30.789 us; speedup 1.0000x reference)
//
#include <hip/hip_runtime.h>
#include <hip/hip_bf16.h>
#include <float.h>

#define EPSV 1e-6f
#define TGT_TILE 2048      // targets per block tile (SoA floats = 16 KB LDS)
#define SRC_TILE 512       // src points per block
#define WAVES 8            // 512 threads
#define SPT 8              // src points per lane (512 / 64)

typedef float f32x2 __attribute__((ext_vector_type(2)));
typedef float f32x4 __attribute__((ext_vector_type(4)));

// Phase A: directed partial Hausdorff (squared), expansion form with PACKED
// fp32 math (v_pk_fma_f32):
//   |s'-t|^2 = |s'|^2 + (|t|^2 - 2 s'.t),   s' = s + eps
// LDS tile is SoA (xs[], ys[]); one ds_read_b128 per array yields 4 targets
// as two adjacent-VGPR f32x2 pairs -> native pk operands (no repack).
// Per 4 targets: 4 pk ops for |t|^2, then per src 2 pk_fma + 2 min3
// (52 instr vs 84 scalar). Every wave's lane l holds the SAME 8 srcs
// (f32x2 splats, compile-time indexed only -> registers, no scratch).
// Waves split the tile 8 ways; cross-wave min via LDS; plain stores. No atomics.
__global__ __launch_bounds__(512, 1) void hausdorff_partial_kernel(
    const float* __restrict__ c1, const float* __restrict__ c2,
    float* __restrict__ ws, int L1, int L2, int STmax, int TTmax, int Lmax) {

    const int b   = blockIdx.y;
    const int B   = gridDim.y;
    const int dir = blockIdx.z;
    const int st  = blockIdx.x % STmax;
    const int tt  = blockIdx.x / STmax;

    const float* src; const float* tgt; int Lsrc, Ltgt;
    if (dir == 0) { src = c2 + (size_t)b * L2 * 2; tgt = c1 + (size_t)b * L1 * 2; Lsrc = L2; Ltgt = L1; }
    else          { src = c1 + (size_t)b * L1 * 2; tgt = c2 + (size_t)b * L2 * 2; Lsrc = L1; Ltgt = L2; }

    const int srcBase = st * SRC_TILE;
    const int tgtBase = tt * TGT_TILE;
    if (srcBase >= Lsrc || tgtBase >= Ltgt) return;   // uniform

    const int lane = threadIdx.x & 63;
    const int w    = threadIdx.x >> 6;

    __shared__ f32x4 xs4[TGT_TILE / 4 + 1];     // SoA target x (16B-aligned)
    __shared__ f32x4 ys4[TGT_TILE / 4 + 1];     // SoA target y
    __shared__ float red[WAVES][SRC_TILE];      // 16 KB
    __shared__ float s2s[SRC_TILE];             // 2 KB
    float* xsf = (float*)xs4;
    float* ysf = (float*)ys4;

    // This lane's 8 src points (identical across waves). f32x2 splats,
    // all indices compile-time (unrolled) -> stays in registers.
    f32x2 nsx2[SPT], nsy2[SPT];
    float s2v[SPT];
    #pragma unroll
    for (int s = 0; s < SPT; ++s) {
        const int j = srcBase + s * 64 + lane;
        if (j < Lsrc) {
            float2 p = ((const float2*)src)[j];
            float sx = p.x + EPSV, sy = p.y + EPSV;
            float nx = -2.0f * sx, ny = -2.0f * sy;
            nsx2[s] = (f32x2){nx, nx};
            nsy2[s] = (f32x2){ny, ny};
            s2v[s]  = fmaf(sx, sx, sy * sy);
        } else {
            nsx2[s] = (f32x2){0.f, 0.f};
            nsy2[s] = (f32x2){0.f, 0.f};
            s2v[s]  = -FLT_MAX;   // phase B never reads j >= Lsrc
        }
    }

    // Stage this block's target tile, SoA; pad to a multiple of 4 with dups.
    const int chunk = min(TGT_TILE, Ltgt - tgtBase);
    const float2* tg = (const float2*)tgt + tgtBase;
    for (int t = threadIdx.x; t < chunk; t += 512) {
        float2 p = tg[t];
        xsf[t] = p.x;
        ysf[t] = p.y;
    }
    const int padded = (chunk + 3) & ~3;
    if ((int)threadIdx.x < padded - chunk) {
        float2 p = tg[chunk - 1];               // dup pad (min-neutral)
        xsf[chunk + threadIdx.x] = p.x;
        ysf[chunk + threadIdx.x] = p.y;
    }
    __syncthreads();

    float mm[SPT];
    #pragma unroll
    for (int s = 0; s < SPT; ++s) mm[s] = FLT_MAX;

    const int P4   = padded >> 2;            // 4-target groups
    const int pbeg = (w * P4) >> 3;
    const int pend = ((w + 1) * P4) >> 3;

#define PROC(xv, yv) {                                                        \
        f32x2 xa = __builtin_shufflevector((xv), (xv), 0, 1);                 \
        f32x2 xb = __builtin_shufflevector((xv), (xv), 2, 3);                 \
        f32x2 ya = __builtin_shufflevector((yv), (yv), 0, 1);                 \
        f32x2 yb = __builtin_shufflevector((yv), (yv), 2, 3);                 \
        f32x2 t2a = __builtin_elementwise_fma(ya, ya, xa * xa);               \
        f32x2 t2b = __builtin_elementwise_fma(yb, yb, xb * xb);               \
        _Pragma("unroll")                                                     \
        for (int s = 0; s < SPT; ++s) {                                       \
            f32x2 da = __builtin_elementwise_fma(xa, nsx2[s],                 \
                           __builtin_elementwise_fma(ya, nsy2[s], t2a));      \
            f32x2 db = __builtin_elementwise_fma(xb, nsx2[s],                 \
                           __builtin_elementwise_fma(yb, nsy2[s], t2b));      \
            mm[s] = fminf(fminf(mm[s], da.x), da.y);  /* -> v_min3_f32 */     \
            mm[s] = fminf(fminf(mm[s], db.x), db.y);                          \
        } }

    int i = pbeg;
    for (; i + 2 <= pend; i += 2) {
        f32x4 xv0 = xs4[i + 0], yv0 = ys4[i + 0];
        f32x4 xv1 = xs4[i + 1], yv1 = ys4[i + 1];
        PROC(xv0, yv0) PROC(xv1, yv1)
    }
    for (; i < pend; ++i) {
        f32x4 xv = xs4[i], yv = ys4[i];
        PROC(xv, yv)
    }
#undef PROC

    // publish per-wave partial mins (+ s2 once)
    #pragma unroll
    for (int s = 0; s < SPT; ++s)
        red[w][s * 64 + lane] = mm[s];
    if (w == 0) {
        #pragma unroll
        for (int s = 0; s < SPT; ++s)
            s2s[s * 64 + lane] = s2v[s];
    }
    __syncthreads();

    // combine across waves; thread t owns src (srcBase + t); plain store
    const int t = threadIdx.x;
    float m = red[0][t];
    #pragma unroll
    for (int ww = 1; ww < WAVES; ++ww)
        m = fminf(m, red[ww][t]);
    const size_t idx = ((size_t)((dir * B + b) * TTmax + tt)) * (size_t)Lmax
                       + (size_t)srcBase + t;
    ws[idx] = s2s[t] + m;
}

// Phase B: per batch, min over tgt-tiles per src, max over srcs and both
// directions, sqrt, scale by resolution.
__global__ __launch_bounds__(512) void hausdorff_reduce_kernel(
    const float* __restrict__ ws, const float* __restrict__ res,
    float* __restrict__ out, int L1, int L2, int TTmax, int Lmax, int B) {

    const int b = blockIdx.x;
    float vmax = 0.0f;   // also serves as the >=0 clamp

    for (int dir = 0; dir < 2; ++dir) {
        const int Lsrc = (dir == 0) ? L2 : L1;
        const int Ltgt = (dir == 0) ? L1 : L2;
        const int nt   = (Ltgt + TGT_TILE - 1) / TGT_TILE;
        const float* base = ws + ((size_t)(dir * B + b) * TTmax) * (size_t)Lmax;
        for (int j = threadIdx.x; j < Lsrc; j += 512) {
            float m = base[j];
            for (int t = 1; t < nt; ++t)
                m = fminf(m, base[(size_t)t * Lmax + j]);
            vmax = fmaxf(vmax, m);
        }
    }

    for (int off = 32; off > 0; off >>= 1)
        vmax = fmaxf(vmax, __shfl_down(vmax, off));

    __shared__ float r[8];
    const int lane = threadIdx.x & 63, w = threadIdx.x >> 6;
    if (lane == 0) r[w] = vmax;
    __syncthreads();
    if (threadIdx.x == 0) {
        float m = r[0];
        #pragma unroll
        for (int i = 1; i < 8; ++i) m = fmaxf(m, r[i]);
        out[b] = sqrtf(fmaxf(m, 0.0f)) * res[b];
    }
}

extern "C" void kernel_launch(void* const* d_in, const int* in_sizes, int n_in,
                              void* d_out, int out_size, void* d_ws, size_t ws_size,
                              hipStream_t stream) {
    const float* c1  = (const float*)d_in[0];
    const float* c2  = (const float*)d_in[1];
    const float* res = (const float*)d_in[2];
    float* out = (float*)d_out;

    const int B  = in_sizes[2];
    const int L1 = in_sizes[0] / (B * 2);
    const int L2 = in_sizes[1] / (B * 2);

    float* ws = (float*)d_ws;

    const int Lmax  = max(L1, L2);
    const int STmax = (Lmax + SRC_TILE - 1) / SRC_TILE;
    const int TTmax = (Lmax + TGT_TILE - 1) / TGT_TILE;

    dim3 gridA(STmax * TTmax, B, 2);
    hipLaunchKernelGGL(hausdorff_partial_kernel, gridA, dim3(512), 0, stream,
                       c1, c2, ws, L1, L2, STmax, TTmax, Lmax);

    hipLaunchKernelGGL(hausdorff_reduce_kernel, dim3(B), dim3(512), 0, stream,
                       ws, res, out, L1, L2, TTmax, Lmax, B);
}

// Round 10
// 27.767 us; speedup vs baseline: 1.1088x; 1.1088x over previous
//
#include <hip/hip_runtime.h>
#include <hip/hip_bf16.h>
#include <float.h>

#define EPSV 1e-6f
#define TGT_TILE 2048      // targets per block tile (SoA floats = 16 KB LDS)
#define SRC_TILE 512       // src points per block
#define WAVES 8            // 512 threads
#define SPT 8              // src points per lane (512 / 64)

typedef float f32x2 __attribute__((ext_vector_type(2)));
typedef float f32x4 __attribute__((ext_vector_type(4)));

// Phase A: directed partial Hausdorff (squared), expansion form with packed
// fp32 math (v_pk_fma_f32):
//   |s'-t|^2 = |s'|^2 + (|t|^2 - 2 s'.t),   s' = s + eps
// LDS tile is SoA (xs[], ys[]); one ds_read_b128 per array yields 4 targets
// as two adjacent-VGPR f32x2 pairs (shufflevector 0,1 / 2,3 = free register
// pair selection). DEPTH-2 REGISTER PREFETCH: slots i+2,i+3 are loaded from
// LDS before computing slots i,i+1, so the ~120-cyc LDS latency is covered
// by ~208 cyc of compute within the same wave (fixes the lockstep stall that
// capped VALUBusy at ~40%). Every wave's lane l holds the SAME 8 srcs
// (compile-time indexed only -> registers). Waves split the tile 8 ways;
// cross-wave min via LDS; plain stores to ws. No atomics, deterministic.
__global__ __launch_bounds__(512, 2) void hausdorff_partial_kernel(
    const float* __restrict__ c1, const float* __restrict__ c2,
    float* __restrict__ ws, int L1, int L2, int STmax, int TTmax, int Lmax) {

    const int b   = blockIdx.y;
    const int B   = gridDim.y;
    const int dir = blockIdx.z;
    const int st  = blockIdx.x % STmax;
    const int tt  = blockIdx.x / STmax;

    const float* src; const float* tgt; int Lsrc, Ltgt;
    if (dir == 0) { src = c2 + (size_t)b * L2 * 2; tgt = c1 + (size_t)b * L1 * 2; Lsrc = L2; Ltgt = L1; }
    else          { src = c1 + (size_t)b * L1 * 2; tgt = c2 + (size_t)b * L2 * 2; Lsrc = L1; Ltgt = L2; }

    const int srcBase = st * SRC_TILE;
    const int tgtBase = tt * TGT_TILE;
    if (srcBase >= Lsrc || tgtBase >= Ltgt) return;   // uniform

    const int lane = threadIdx.x & 63;
    const int w    = threadIdx.x >> 6;

    __shared__ f32x4 xs4[TGT_TILE / 4 + 1];     // SoA target x (+1: prefetch overread)
    __shared__ f32x4 ys4[TGT_TILE / 4 + 1];     // SoA target y
    __shared__ float red[WAVES][SRC_TILE];      // 16 KB
    __shared__ float s2s[SRC_TILE];             // 2 KB
    float* xsf = (float*)xs4;
    float* ysf = (float*)ys4;

    // This lane's 8 src points (identical across waves). f32x2 splats,
    // all indices compile-time (unrolled) -> stays in registers.
    f32x2 nsx2[SPT], nsy2[SPT];
    float s2v[SPT];
    #pragma unroll
    for (int s = 0; s < SPT; ++s) {
        const int j = srcBase + s * 64 + lane;
        if (j < Lsrc) {
            float2 p = ((const float2*)src)[j];
            float sx = p.x + EPSV, sy = p.y + EPSV;
            float nx = -2.0f * sx, ny = -2.0f * sy;
            nsx2[s] = (f32x2){nx, nx};
            nsy2[s] = (f32x2){ny, ny};
            s2v[s]  = fmaf(sx, sx, sy * sy);
        } else {
            nsx2[s] = (f32x2){0.f, 0.f};
            nsy2[s] = (f32x2){0.f, 0.f};
            s2v[s]  = -FLT_MAX;   // phase B never reads j >= Lsrc
        }
    }

    // Stage this block's target tile, SoA; pad to a multiple of 4 with dups.
    const int chunk = min(TGT_TILE, Ltgt - tgtBase);
    const float2* tg = (const float2*)tgt + tgtBase;
    for (int t = threadIdx.x; t < chunk; t += 512) {
        float2 p = tg[t];
        xsf[t] = p.x;
        ysf[t] = p.y;
    }
    const int padded = (chunk + 3) & ~3;
    if ((int)threadIdx.x < padded - chunk) {
        float2 p = tg[chunk - 1];               // dup pad (min-neutral)
        xsf[chunk + threadIdx.x] = p.x;
        ysf[chunk + threadIdx.x] = p.y;
    }
    __syncthreads();

    float mm[SPT];
    #pragma unroll
    for (int s = 0; s < SPT; ++s) mm[s] = FLT_MAX;

    const int P4   = padded >> 2;            // 4-target groups
    const int pbeg = (w * P4) >> 3;
    const int pend = ((w + 1) * P4) >> 3;

#define PROC(xv, yv) {                                                        \
        f32x2 xa_ = __builtin_shufflevector((xv), (xv), 0, 1);                \
        f32x2 xb_ = __builtin_shufflevector((xv), (xv), 2, 3);                \
        f32x2 ya_ = __builtin_shufflevector((yv), (yv), 0, 1);                \
        f32x2 yb_ = __builtin_shufflevector((yv), (yv), 2, 3);                \
        f32x2 t2a = __builtin_elementwise_fma(ya_, ya_, xa_ * xa_);           \
        f32x2 t2b = __builtin_elementwise_fma(yb_, yb_, xb_ * xb_);           \
        _Pragma("unroll")                                                     \
        for (int s = 0; s < SPT; ++s) {                                       \
            f32x2 da = __builtin_elementwise_fma(xa_, nsx2[s],                \
                           __builtin_elementwise_fma(ya_, nsy2[s], t2a));     \
            f32x2 db = __builtin_elementwise_fma(xb_, nsx2[s],                \
                           __builtin_elementwise_fma(yb_, nsy2[s], t2b));     \
            mm[s] = fminf(fminf(mm[s], da.x), da.y);  /* -> v_min3_f32 */     \
            mm[s] = fminf(fminf(mm[s], db.x), db.y);                          \
        } }

    if (pbeg < pend) {
        // depth-2 software pipeline: loads lead computation by 2 slots
        f32x4 xa = xs4[pbeg + 0], ya = ys4[pbeg + 0];   // idx <= 512: in-bounds
        f32x4 xb = xs4[pbeg + 1], yb = ys4[pbeg + 1];   // (garbage ok if unused)
        int i = pbeg;
        for (; i + 2 < pend; i += 2) {
            f32x4 xc = xs4[i + 2], yc = ys4[i + 2];
            f32x4 xd = xs4[i + 3], yd = ys4[i + 3];
            PROC(xa, ya)
            PROC(xb, yb)
            xa = xc; ya = yc; xb = xd; yb = yd;
        }
        PROC(xa, ya)
        if (i + 1 < pend) { PROC(xb, yb) }
    }
#undef PROC

    // publish per-wave partial mins (+ s2 once)
    #pragma unroll
    for (int s = 0; s < SPT; ++s)
        red[w][s * 64 + lane] = mm[s];
    if (w == 0) {
        #pragma unroll
        for (int s = 0; s < SPT; ++s)
            s2s[s * 64 + lane] = s2v[s];
    }
    __syncthreads();

    // combine across waves; thread t owns src (srcBase + t); plain store
    const int t = threadIdx.x;
    float m = red[0][t];
    #pragma unroll
    for (int ww = 1; ww < WAVES; ++ww)
        m = fminf(m, red[ww][t]);
    const size_t idx = ((size_t)((dir * B + b) * TTmax + tt)) * (size_t)Lmax
                       + (size_t)srcBase + t;
    ws[idx] = s2s[t] + m;
}

// Phase B: per batch, min over tgt-tiles per src, max over srcs and both
// directions, sqrt, scale by resolution. float4 loads where aligned.
__global__ __launch_bounds__(512) void hausdorff_reduce_kernel(
    const float* __restrict__ ws, const float* __restrict__ res,
    float* __restrict__ out, int L1, int L2, int TTmax, int Lmax, int B) {

    const int b = blockIdx.x;
    float vmax = 0.0f;   // also serves as the >=0 clamp

    for (int dir = 0; dir < 2; ++dir) {
        const int Lsrc = (dir == 0) ? L2 : L1;
        const int Ltgt = (dir == 0) ? L1 : L2;
        const int nt   = (Ltgt + TGT_TILE - 1) / TGT_TILE;
        const float* base = ws + ((size_t)(dir * B + b) * TTmax) * (size_t)Lmax;

        if ((Lmax & 3) == 0) {                    // 16B-aligned fast path
            const int n4 = Lsrc >> 2;
            for (int j = threadIdx.x; j < n4; j += 512) {
                float4 m4 = ((const float4*)base)[j];
                for (int t = 1; t < nt; ++t) {
                    float4 v = ((const float4*)(base + (size_t)t * Lmax))[j];
                    m4.x = fminf(m4.x, v.x); m4.y = fminf(m4.y, v.y);
                    m4.z = fminf(m4.z, v.z); m4.w = fminf(m4.w, v.w);
                }
                vmax = fmaxf(vmax,
                             fmaxf(fmaxf(m4.x, m4.y), fmaxf(m4.z, m4.w)));
            }
            for (int j = (n4 << 2) + threadIdx.x; j < Lsrc; j += 512) {
                float m = base[j];
                for (int t = 1; t < nt; ++t)
                    m = fminf(m, base[(size_t)t * Lmax + j]);
                vmax = fmaxf(vmax, m);
            }
        } else {
            for (int j = threadIdx.x; j < Lsrc; j += 512) {
                float m = base[j];
                for (int t = 1; t < nt; ++t)
                    m = fminf(m, base[(size_t)t * Lmax + j]);
                vmax = fmaxf(vmax, m);
            }
        }
    }

    for (int off = 32; off > 0; off >>= 1)
        vmax = fmaxf(vmax, __shfl_down(vmax, off));

    __shared__ float r[8];
    const int lane = threadIdx.x & 63, w = threadIdx.x >> 6;
    if (lane == 0) r[w] = vmax;
    __syncthreads();
    if (threadIdx.x == 0) {
        float m = r[0];
        #pragma unroll
        for (int i = 1; i < 8; ++i) m = fmaxf(m, r[i]);
        out[b] = sqrtf(fmaxf(m, 0.0f)) * res[b];
    }
}

extern "C" void kernel_launch(void* const* d_in, const int* in_sizes, int n_in,
                              void* d_out, int out_size, void* d_ws, size_t ws_size,
                              hipStream_t stream) {
    const float* c1  = (const float*)d_in[0];
    const float* c2  = (const float*)d_in[1];
    const float* res = (const float*)d_in[2];
    float* out = (float*)d_out;

    const int B  = in_sizes[2];
    const int L1 = in_sizes[0] / (B * 2);
    const int L2 = in_sizes[1] / (B * 2);

    float* ws = (float*)d_ws;

    const int Lmax  = max(L1, L2);
    const int STmax = (Lmax + SRC_TILE - 1) / SRC_TILE;
    const int TTmax = (Lmax + TGT_TILE - 1) / TGT_TILE;

    dim3 gridA(STmax * TTmax, B, 2);
    hipLaunchKernelGGL(hausdorff_partial_kernel, gridA, dim3(512), 0, stream,
                       c1, c2, ws, L1, L2, STmax, TTmax, Lmax);

    hipLaunchKernelGGL(hausdorff_reduce_kernel, dim3(B), dim3(512), 0, stream,
                       ws, res, out, L1, L2, TTmax, Lmax, B);
}